// Round 1
// baseline (1299.159 us; speedup 1.0000x reference)
//
#include <hip/hip_runtime.h>
#include <hip/hip_bf16.h>

#define D 256
#define TE 64          // edges per block
#define BK 64          // K-chunk
#define KTOT 768       // folded K: [E | Hh*E | Hh]
#define NCHUNK 12      // KTOT/BK
#define LEAKY 0.01f
#define EPS 1e-5f

typedef float f32x4 __attribute__((ext_vector_type(4)));
typedef short s16x8 __attribute__((ext_vector_type(8)));

__device__ __forceinline__ unsigned short f2bf(float f){
  union { float f; unsigned int u; } v; v.f = f;
  unsigned int u = v.u;
  return (unsigned short)((u + 0x7fffu + ((u >> 16) & 1u)) >> 16);
}
__device__ __forceinline__ unsigned int pack2(float a, float b){
  return (unsigned int)f2bf(a) | ((unsigned int)f2bf(b) << 16);
}

// Fold W (d,4d) into Wc[dir][j][k] bf16, k-blocks: [W2+W3 | W4 | W1+W3]
__global__ void prep_w(const float* __restrict__ Wf, const float* __restrict__ Wb,
                       unsigned short* __restrict__ Wc)
{
  int i = blockIdx.x * 256 + threadIdx.x;      // 2*D*KTOT total
  int dir = i / (D * KTOT);
  int rem = i - dir * (D * KTOT);
  int j = rem / KTOT;
  int k = rem - j * KTOT;
  const float* W = dir ? Wb : Wf;
  const float* row = W + (long)j * (4 * D);
  float v;
  if (k < 256)      v = row[256 + k] + row[512 + k]; // E coeff
  else if (k < 512) v = row[512 + k];                // Hh*E coeff (=row[768+(k-256)])
  else              v = row[k - 512] + row[k];       // Hh coeff
  Wc[i] = f2bf(v);
}

__global__ void count_deg(const int* __restrict__ ht, float* __restrict__ cnt, int n_edges)
{
  int e = blockIdx.x * 256 + threadIdx.x;
  if (e < n_edges){
    atomicAdd(&cnt[ht[2*e]],   1.0f);  // head receives back-message
    atomicAdd(&cnt[ht[2*e+1]], 1.0f);  // tail receives fwd-message
  }
}

__global__ __launch_bounds__(256) void edge_gemm(
    const float* __restrict__ H, const float* __restrict__ E,
    const int* __restrict__ ht, const float* __restrict__ bias_f,
    const float* __restrict__ bias_b, const unsigned short* __restrict__ Wc,
    float* __restrict__ agg, int n_edges)
{
  __shared__ char sA[TE * BK * 2];   // 8 KB, XOR-swizzled
  __shared__ char sB[D * BK * 2];    // 32 KB, XOR-swizzled
  __shared__ int sHead[TE], sTail[TE];

  const int tid = threadIdx.x;
  const long e0 = (long)blockIdx.x * TE;

  if (tid < TE){
    long e = e0 + tid; if (e >= n_edges) e = n_edges - 1;
    sHead[tid] = ht[2*e]; sTail[tid] = ht[2*e+1];
  }
  __syncthreads();

  const int lane = tid & 63;
  const int wave = tid >> 6;
  const int n0 = wave * 64;        // wave's 64-col output slice
  const int rlo = lane & 15;
  const int khi = lane >> 4;

  const int srow = tid >> 2;       // staging: 4 threads per edge-row
  const int sq = tid & 3;

  for (int dir = 0; dir < 2; ++dir){
    f32x4 acc[4][4];
    #pragma unroll
    for (int mi = 0; mi < 4; ++mi)
      #pragma unroll
      for (int ni = 0; ni < 4; ++ni)
        acc[mi][ni] = (f32x4){0.f, 0.f, 0.f, 0.f};

    const unsigned short* W = Wc + (long)dir * D * KTOT;
    long es = e0 + srow; if (es >= n_edges) es = n_edges - 1;
    const int hidx = dir ? sTail[srow] : sHead[srow];
    const float* Erow = E + es * D;
    const float* Hrow = H + (long)hidx * D;

    for (int c = 0; c < NCHUNK; ++c){
      __syncthreads();             // protect previous chunk's reads
      // ---- stage B chunk: all 256 out-rows, k-slice [c*64, c*64+64)
      {
        const int ch = tid & 7;    // 16B chunk within row
        const int jb = tid >> 3;
        #pragma unroll
        for (int p = 0; p < 8; ++p){
          int j = p * 32 + jb;
          const uint4 v = *(const uint4*)(W + (long)j * KTOT + c * BK + ch * 8);
          int off = (j * (BK * 2) + ch * 16) ^ ((j & 7) << 4);
          *(uint4*)(sB + off) = v;
        }
      }
      // ---- stage A chunk: 64 edge-rows, built from E / Hh*E / Hh
      {
        const int b = c >> 2;             // 0:E  1:Hh*E  2:Hh
        const int c0 = (c & 3) * 64;      // column block within [0,256)
        #pragma unroll
        for (int it = 0; it < 4; ++it){
          int col = c0 + sq * 4 + it * 16;
          float4 v;
          if (b == 0) v = *(const float4*)(Erow + col);
          else if (b == 1){
            float4 ev = *(const float4*)(Erow + col);
            float4 hv = *(const float4*)(Hrow + col);
            v = make_float4(ev.x*hv.x, ev.y*hv.y, ev.z*hv.z, ev.w*hv.w);
          } else v = *(const float4*)(Hrow + col);
          uint2 w; w.x = pack2(v.x, v.y); w.y = pack2(v.z, v.w);
          int off = (srow * (BK * 2) + (sq * 4 + it * 16) * 2) ^ ((srow & 7) << 4);
          *(uint2*)(sA + off) = w;
        }
      }
      __syncthreads();
      // ---- MFMA: 2 k-steps of 32
      #pragma unroll
      for (int ks = 0; ks < 2; ++ks){
        const int kb = (ks * 32 + khi * 8) * 2;   // byte offset of k
        s16x8 af[4], bfr[4];
        #pragma unroll
        for (int mi = 0; mi < 4; ++mi){
          int row = mi * 16 + rlo;
          af[mi] = *(const s16x8*)(sA + ((row * (BK * 2) + kb) ^ ((row & 7) << 4)));
        }
        #pragma unroll
        for (int ni = 0; ni < 4; ++ni){
          int j = n0 + ni * 16 + rlo;
          bfr[ni] = *(const s16x8*)(sB + ((j * (BK * 2) + kb) ^ ((j & 7) << 4)));
        }
        #pragma unroll
        for (int mi = 0; mi < 4; ++mi)
          #pragma unroll
          for (int ni = 0; ni < 4; ++ni)
            acc[mi][ni] = __builtin_amdgcn_mfma_f32_16x16x32_bf16(
                af[mi], bfr[ni], acc[mi][ni], 0, 0, 0);
      }
    }
    // ---- epilogue: scatter messages (+bias) to agg[dst]
    const float* bias = dir ? bias_b : bias_f;
    #pragma unroll
    for (int ni = 0; ni < 4; ++ni){
      const int n = n0 + ni * 16 + rlo;
      const float bv = bias[n];
      #pragma unroll
      for (int mi = 0; mi < 4; ++mi){
        #pragma unroll
        for (int r = 0; r < 4; ++r){
          int m = mi * 16 + khi * 4 + r;
          long e = e0 + m;
          if (e < n_edges){
            int dst = dir ? sHead[m] : sTail[m];
            atomicAdd(agg + (long)dst * D + n, acc[mi][ni][r] + bv);
          }
        }
      }
    }
    __syncthreads();
  }
}

__global__ __launch_bounds__(256) void finish(
    const float* __restrict__ agg, const float* __restrict__ cnt,
    const float* __restrict__ H, const float* __restrict__ gamma,
    const float* __restrict__ beta, float* __restrict__ out)
{
  const int n = blockIdx.x;
  const int j = threadIdx.x;
  float c = cnt[n]; c = c < 1.f ? 1.f : c;
  float a = agg[(long)n * D + j] / c;
  float x = (a > 0.f ? a : LEAKY * a) + H[(long)n * D + j];
  float s1 = x, s2 = x * x;
  #pragma unroll
  for (int off = 32; off > 0; off >>= 1){
    s1 += __shfl_xor(s1, off);
    s2 += __shfl_xor(s2, off);
  }
  __shared__ float rs[8];
  if ((j & 63) == 0){ rs[j >> 6] = s1; rs[4 + (j >> 6)] = s2; }
  __syncthreads();
  float t1 = rs[0] + rs[1] + rs[2] + rs[3];
  float t2 = rs[4] + rs[5] + rs[6] + rs[7];
  float mu = t1 * (1.f / D);
  float var = t2 * (1.f / D) - mu * mu;
  float r = rsqrtf(var + EPS);
  out[(long)n * D + j] = (x - mu) * r * gamma[j] + beta[j];
}

extern "C" void kernel_launch(void* const* d_in, const int* in_sizes, int n_in,
                              void* d_out, int out_size, void* d_ws, size_t ws_size,
                              hipStream_t stream)
{
  const float* H      = (const float*)d_in[0];
  const float* E      = (const float*)d_in[1];
  const int*   ht     = (const int*)d_in[2];
  const float* W_fwd  = (const float*)d_in[3];
  const float* b_fwd  = (const float*)d_in[4];
  const float* W_back = (const float*)d_in[5];
  const float* b_back = (const float*)d_in[6];
  const float* gamma  = (const float*)d_in[7];
  const float* beta   = (const float*)d_in[8];
  float* out = (float*)d_out;

  const int n_nodes = in_sizes[0] / D;
  const int n_edges = in_sizes[2] / 2;

  float* agg = (float*)d_ws;
  float* cnt = agg + (size_t)n_nodes * D;
  size_t woff = ((size_t)n_nodes * D + n_nodes) * sizeof(float);
  woff = (woff + 15) & ~(size_t)15;
  unsigned short* Wc = (unsigned short*)((char*)d_ws + woff);

  hipMemsetAsync(d_ws, 0, ((size_t)n_nodes * D + n_nodes) * sizeof(float), stream);
  prep_w<<<(2 * D * KTOT) / 256, 256, 0, stream>>>(W_fwd, W_back, Wc);
  count_deg<<<(n_edges + 255) / 256, 256, 0, stream>>>(ht, cnt, n_edges);
  edge_gemm<<<(n_edges + TE - 1) / TE, 256, 0, stream>>>(H, E, ht, b_fwd, b_back, Wc, agg, n_edges);
  finish<<<n_nodes, 256, 0, stream>>>(agg, cnt, H, gamma, beta, out);
}

// Round 2
// 967.844 us; speedup vs baseline: 1.3423x; 1.3423x over previous
//
#include <hip/hip_runtime.h>
#include <hip/hip_bf16.h>

#define D 256
#define TE 128         // edges per tile
#define NB 128         // output cols per block (colhalf)
#define BK 64          // K-chunk
#define KTOT 768       // folded K: [E | Hh*E | Hh]
#define NCHUNK 12      // KTOT/BK
#define LEAKY 0.01f
#define EPS 1e-5f

typedef float f32x4 __attribute__((ext_vector_type(4)));
typedef short s16x8 __attribute__((ext_vector_type(8)));

#define GLL16(g, l) __builtin_amdgcn_global_load_lds(                      \
    (const __attribute__((address_space(1))) unsigned int*)(g),            \
    (__attribute__((address_space(3))) unsigned int*)(l), 16, 0, 0)

__device__ __forceinline__ unsigned short f2bf(float f){
  union { float f; unsigned int u; } v; v.f = f;
  unsigned int u = v.u;
  return (unsigned short)((u + 0x7fffu + ((u >> 16) & 1u)) >> 16);
}
__device__ __forceinline__ unsigned int pack2(float a, float b){
  return (unsigned int)f2bf(a) | ((unsigned int)f2bf(b) << 16);
}

// Build pre-swizzled LDS images of folded weights.
// Tile (q,c), q = dir*2+colhalf: 16KB block = LDS bytes of sB for chunk c.
// Within tile: boff = (j*128 + k*2) ^ ((j&7)<<4),  j = local col, k = local K.
__global__ void prep_w(const float* __restrict__ Wf, const float* __restrict__ Wb,
                       unsigned short* __restrict__ Wimg)
{
  int i = blockIdx.x * 256 + threadIdx.x;       // 2*2*12*128*64 = 393216
  int inner = i & 8191;                         // j*64 + k
  int tileIdx = i >> 13;                        // q*12 + c
  int c = tileIdx % 12;
  int q = tileIdx / 12;
  int dir = q >> 1, h = q & 1;
  int j = inner >> 6, k = inner & 63;
  int col = h * NB + j;
  int kk = c * BK + k;                          // global folded-K index
  const float* row = (dir ? Wb : Wf) + (long)col * (4 * D);
  float v;
  if (kk < 256)      v = row[256 + kk] + row[512 + kk];  // E coeff
  else if (kk < 512) v = row[512 + kk];                  // Hh*E coeff (=768+(kk-256))
  else               v = row[kk - 512] + row[kk];        // Hh coeff
  int boff = ((j * 128 + k * 2) ^ ((j & 7) << 4));
  *(unsigned short*)((char*)Wimg + (size_t)tileIdx * 16384 + boff) = f2bf(v);
}

__global__ void count_deg(const int* __restrict__ ht, float* __restrict__ cnt, int n_edges)
{
  int e = blockIdx.x * 256 + threadIdx.x;
  if (e < n_edges){
    atomicAdd(&cnt[ht[2*e]],   1.0f);
    atomicAdd(&cnt[ht[2*e+1]], 1.0f);
  }
}

__global__ __launch_bounds__(256) void edge_gemm(
    const float* __restrict__ H, const float* __restrict__ E,
    const int* __restrict__ ht, const float* __restrict__ bias_f,
    const float* __restrict__ bias_b, const unsigned short* __restrict__ Wimg,
    float* __restrict__ agg, int n_edges)
{
  __shared__ char sA[2][16384];
  __shared__ char sB[2][16384];
  __shared__ int sIdx[2][TE];

  const int bid  = blockIdx.x;
  const int tile = bid >> 2;
  const int q    = bid & 3;          // dir*2 + colhalf
  const int dir  = q >> 1;
  const int h    = q & 1;
  const long e0  = (long)tile * TE;

  const int tid  = threadIdx.x;
  const int lane = tid & 63;
  const int wave = tid >> 6;

  if (tid < TE){
    long e = e0 + tid; if (e >= n_edges) e = n_edges - 1;
    sIdx[0][tid] = ht[2*e]; sIdx[1][tid] = ht[2*e+1];
  }
  __syncthreads();

  // Per-thread A-staging rows: it=0..7 -> row = wave*32 + it*4 + (lane>>4)
  const float* eptr[8]; const float* hptr[8];
  #pragma unroll
  for (int it = 0; it < 8; ++it){
    int row = wave * 32 + it * 4 + (lane >> 4);
    long e = e0 + row; if (e >= n_edges) e = n_edges - 1;
    eptr[it] = E + e * D;
    int idx = dir ? sIdx[1][row] : sIdx[0][row];
    hptr[it] = H + (long)idx * D;
  }

  const unsigned short* wq = Wimg + (size_t)q * NCHUNK * 8192;

  f32x4 acc[4][4];
  #pragma unroll
  for (int mi = 0; mi < 4; ++mi)
    #pragma unroll
    for (int ni = 0; ni < 4; ++ni)
      acc[mi][ni] = (f32x4){0.f, 0.f, 0.f, 0.f};

  const int rlo = lane & 15;
  const int khi = lane >> 4;
  const int wm = wave >> 1;
  const int wn = wave & 1;

  #define STAGE_B(c, buf) {                                                  \
    const char* srcb = (const char*)wq + (size_t)(c) * 16384                 \
                       + wave * 4096 + lane * 16;                            \
    char* db = &sB[buf][wave * 4096];                                        \
    GLL16(srcb,        db);                                                  \
    GLL16(srcb + 1024, db + 1024);                                           \
    GLL16(srcb + 2048, db + 2048);                                           \
    GLL16(srcb + 3072, db + 3072);                                           \
  }

  #define STAGE_A(c, buf) {                                                  \
    const int b  = (c) >> 2;                                                 \
    const int c0 = ((c) & 3) * 64 + rlo * 4;                                 \
    _Pragma("unroll")                                                        \
    for (int it = 0; it < 8; ++it){                                          \
      int row = wave * 32 + it * 4 + khi;                                    \
      float4 v;                                                              \
      if (b == 0)      v = *(const float4*)(eptr[it] + c0);                  \
      else if (b == 2) v = *(const float4*)(hptr[it] + c0);                  \
      else {                                                                 \
        float4 ev = *(const float4*)(eptr[it] + c0);                         \
        float4 hv = *(const float4*)(hptr[it] + c0);                         \
        v = make_float4(ev.x*hv.x, ev.y*hv.y, ev.z*hv.z, ev.w*hv.w);         \
      }                                                                      \
      uint2 w; w.x = pack2(v.x, v.y); w.y = pack2(v.z, v.w);                 \
      int off = (row * 128 + rlo * 8) ^ ((row & 7) << 4);                    \
      *(uint2*)(&sA[buf][off]) = w;                                          \
    }                                                                        \
  }

  STAGE_B(0, 0);
  STAGE_A(0, 0);
  __syncthreads();

  for (int c = 0; c < NCHUNK; ++c){
    const int cur = c & 1;
    if (c + 1 < NCHUNK){
      STAGE_B(c + 1, cur ^ 1);
      STAGE_A(c + 1, cur ^ 1);
    }
    #pragma unroll
    for (int ks = 0; ks < 2; ++ks){
      const int kb = (ks * 32 + khi * 8) * 2;
      s16x8 af[4], bfr[4];
      #pragma unroll
      for (int mi = 0; mi < 4; ++mi){
        int row = wm * 64 + mi * 16 + rlo;
        af[mi] = *(const s16x8*)(&sA[cur][(row * 128 + kb) ^ ((row & 7) << 4)]);
      }
      #pragma unroll
      for (int ni = 0; ni < 4; ++ni){
        int col = wn * 64 + ni * 16 + rlo;
        bfr[ni] = *(const s16x8*)(&sB[cur][(col * 128 + kb) ^ ((col & 7) << 4)]);
      }
      #pragma unroll
      for (int mi = 0; mi < 4; ++mi)
        #pragma unroll
        for (int ni = 0; ni < 4; ++ni)
          acc[mi][ni] = __builtin_amdgcn_mfma_f32_16x16x32_bf16(
              af[mi], bfr[ni], acc[mi][ni], 0, 0, 0);
    }
    __syncthreads();
  }

  // Epilogue: scatter (+bias) to agg[dst]
  const float* bias = dir ? bias_b : bias_f;
  #pragma unroll
  for (int ni = 0; ni < 4; ++ni){
    const int gcol = h * NB + wn * 64 + ni * 16 + rlo;
    const float bv = bias[gcol];
    #pragma unroll
    for (int mi = 0; mi < 4; ++mi){
      #pragma unroll
      for (int r = 0; r < 4; ++r){
        int m = wm * 64 + mi * 16 + khi * 4 + r;
        long e = e0 + m;
        if (e < n_edges){
          int dst = dir ? sIdx[0][m] : sIdx[1][m];
          atomicAdd(agg + (long)dst * D + gcol, acc[mi][ni][r] + bv);
        }
      }
    }
  }
  #undef STAGE_A
  #undef STAGE_B
}

__global__ __launch_bounds__(256) void finish(
    const float* __restrict__ agg, const float* __restrict__ cnt,
    const float* __restrict__ H, const float* __restrict__ gamma,
    const float* __restrict__ beta, float* __restrict__ out)
{
  const int n = blockIdx.x;
  const int j = threadIdx.x;
  float c = cnt[n]; c = c < 1.f ? 1.f : c;
  float a = agg[(long)n * D + j] / c;
  float x = (a > 0.f ? a : LEAKY * a) + H[(long)n * D + j];
  float s1 = x, s2 = x * x;
  #pragma unroll
  for (int off = 32; off > 0; off >>= 1){
    s1 += __shfl_xor(s1, off);
    s2 += __shfl_xor(s2, off);
  }
  __shared__ float rs[8];
  if ((j & 63) == 0){ rs[j >> 6] = s1; rs[4 + (j >> 6)] = s2; }
  __syncthreads();
  float t1 = rs[0] + rs[1] + rs[2] + rs[3];
  float t2 = rs[4] + rs[5] + rs[6] + rs[7];
  float mu = t1 * (1.f / D);
  float var = t2 * (1.f / D) - mu * mu;
  float r = rsqrtf(var + EPS);
  out[(long)n * D + j] = (x - mu) * r * gamma[j] + beta[j];
}

extern "C" void kernel_launch(void* const* d_in, const int* in_sizes, int n_in,
                              void* d_out, int out_size, void* d_ws, size_t ws_size,
                              hipStream_t stream)
{
  const float* H      = (const float*)d_in[0];
  const float* E      = (const float*)d_in[1];
  const int*   ht     = (const int*)d_in[2];
  const float* W_fwd  = (const float*)d_in[3];
  const float* b_fwd  = (const float*)d_in[4];
  const float* W_back = (const float*)d_in[5];
  const float* b_back = (const float*)d_in[6];
  const float* gamma  = (const float*)d_in[7];
  const float* beta   = (const float*)d_in[8];
  float* out = (float*)d_out;

  const int n_nodes = in_sizes[0] / D;
  const int n_edges = in_sizes[2] / 2;

  float* agg = (float*)d_ws;
  float* cnt = agg + (size_t)n_nodes * D;
  size_t woff = ((size_t)n_nodes * D + n_nodes) * sizeof(float);
  woff = (woff + 255) & ~(size_t)255;
  unsigned short* Wimg = (unsigned short*)((char*)d_ws + woff);

  hipMemsetAsync(d_ws, 0, ((size_t)n_nodes * D + n_nodes) * sizeof(float), stream);
  prep_w<<<(2 * 2 * NCHUNK * NB * BK) / 256, 256, 0, stream>>>(W_fwd, W_back, Wimg);
  count_deg<<<(n_edges + 255) / 256, 256, 0, stream>>>(ht, cnt, n_edges);

  const int ntiles = (n_edges + TE - 1) / TE;
  edge_gemm<<<ntiles * 4, 256, 0, stream>>>(H, E, ht, b_fwd, b_back, Wimg, agg, n_edges);
  finish<<<n_nodes, 256, 0, stream>>>(agg, cnt, H, gamma, beta, out);
}

// Round 3
// 711.099 us; speedup vs baseline: 1.8270x; 1.3611x over previous
//
#include <hip/hip_runtime.h>
#include <hip/hip_bf16.h>

#define D 256
#define TE 128         // edges per tile
#define BK 64          // K-chunk
#define NCHUNK 12      // 4 groups x [E | E*H | H]
#define LEAKY 0.01f
#define EPS 1e-5f

typedef float f32x4 __attribute__((ext_vector_type(4)));
typedef short s16x8 __attribute__((ext_vector_type(8)));

#define GLL16(g, l) __builtin_amdgcn_global_load_lds(                      \
    (const __attribute__((address_space(1))) unsigned int*)(g),            \
    (__attribute__((address_space(3))) unsigned int*)(l), 16, 0, 0)

__device__ __forceinline__ unsigned short f2bf(float f){
  union { float f; unsigned int u; } v; v.f = f;
  unsigned int u = v.u;
  return (unsigned short)((u + 0x7fffu + ((u >> 16) & 1u)) >> 16);
}
__device__ __forceinline__ unsigned int pack2(float a, float b){
  return (unsigned int)f2bf(a) | ((unsigned int)f2bf(b) << 16);
}

// Pre-swizzled LDS images of folded weights.
// K reorder: group g in 0..3, parts [E_g | (E*H)_g | H_g], chunk c = g*3+part.
// Image tile t = dir*12 + c (32 KB each): boff = (j*128 + k*2) ^ ((j&7)<<4).
__global__ void prep_w(const float* __restrict__ Wf, const float* __restrict__ Wb,
                       unsigned short* __restrict__ Wimg)
{
  int i = blockIdx.x * 256 + threadIdx.x;       // 2*12*256*64 = 393216
  int inner = i & 16383;                        // j*64 + k
  int t = i >> 14;                              // dir*12 + c
  int c = t % 12, dir = t / 12;
  int g = c / 3, part = c - g * 3;
  int j = inner >> 6, k = inner & 63;
  int x = g * 64 + k;                           // original 0..255 feature index
  const float* row = (dir ? Wb : Wf) + (long)j * (4 * D);
  // raw = [Hh | E | Hh+E | Hh*E]:
  float v;
  if (part == 0)      v = row[256 + x] + row[512 + x];   // E coeff
  else if (part == 1) v = row[768 + x];                  // Hh*E coeff
  else                v = row[x] + row[512 + x];         // Hh coeff
  int boff = (j * 128 + k * 2) ^ ((j & 7) << 4);
  *(unsigned short*)((char*)Wimg + (size_t)t * 32768 + boff) = f2bf(v);
}

__global__ void count_deg(const int* __restrict__ ht, float* __restrict__ cnt, int n_edges)
{
  int e = blockIdx.x * 256 + threadIdx.x;
  if (e < n_edges){
    atomicAdd(&cnt[ht[2*e]],   1.0f);
    atomicAdd(&cnt[ht[2*e+1]], 1.0f);
  }
}

__global__ __launch_bounds__(1024) void edge_gemm(
    const float* __restrict__ H, const float* __restrict__ E,
    const int* __restrict__ ht, const float* __restrict__ bias_f,
    const float* __restrict__ bias_b, const unsigned short* __restrict__ Wimg,
    float* __restrict__ agg, int n_edges)
{
  __shared__ char sA[2][16384];   // 128 rows x 64 k
  __shared__ char sB[2][32768];   // 256 cols x 64 k
  __shared__ int sIdx[2][TE];

  const int bid = blockIdx.x;
  const long e0 = (long)(bid >> 1) * TE;
  const int dir = bid & 1;

  const int tid  = threadIdx.x;
  const int lane = tid & 63;
  const int wave = tid >> 6;      // 0..15

  if (tid < TE){
    long e = e0 + tid; if (e >= n_edges) e = n_edges - 1;
    sIdx[0][tid] = ht[2*e]; sIdx[1][tid] = ht[2*e+1];
  }
  __syncthreads();

  // A staging: thread -> 2 rows x 4 cols. cg = col group, rows rg*2+i.
  const int cg = tid & 15;
  const int rg = tid >> 4;        // 0..63
  int eidx[2]; int hidx[2];
  #pragma unroll
  for (int i = 0; i < 2; ++i){
    int row = rg * 2 + i;
    long e = e0 + row; if (e >= n_edges) e = n_edges - 1;
    eidx[i] = (int)e;
    hidx[i] = sIdx[dir][row];     // dir0: H[head] (fwd), dir1: H[tail] (back)
  }
  const char* wq = (const char*)Wimg + (size_t)dir * NCHUNK * 32768;

  f32x4 acc[2][4];
  #pragma unroll
  for (int mi = 0; mi < 2; ++mi)
    #pragma unroll
    for (int ni = 0; ni < 4; ++ni)
      acc[mi][ni] = (f32x4){0.f, 0.f, 0.f, 0.f};

  float4 Ev[2];

  const int rlo = lane & 15;
  const int khi = lane >> 4;
  const int wm = wave >> 2;       // 0..3: 32-row slab
  const int wn = wave & 3;        // 0..3: 64-col slab

  #define STAGE_B(c, buf) {                                                  \
    const char* srcb = wq + (size_t)(c) * 32768 + wave * 1024 + lane * 16;   \
    char* db = &sB[buf][wave * 1024];                                        \
    GLL16(srcb,         db);                                                 \
    GLL16(srcb + 16384, db + 16384);                                         \
  }

  #define STAGE_A(c, buf) {                                                  \
    const int g = (c) / 3, part = (c) - g * 3;                               \
    _Pragma("unroll")                                                        \
    for (int i = 0; i < 2; ++i){                                             \
      int row = rg * 2 + i;                                                  \
      float4 v;                                                              \
      if (part == 0){                                                        \
        Ev[i] = *(const float4*)(E + (long)eidx[i] * D + g * 64 + cg * 4);   \
        v = Ev[i];                                                           \
      } else {                                                               \
        float4 hv = *(const float4*)(H + (long)hidx[i] * D + g * 64 + cg * 4);\
        if (part == 1) v = make_float4(Ev[i].x*hv.x, Ev[i].y*hv.y,           \
                                       Ev[i].z*hv.z, Ev[i].w*hv.w);          \
        else v = hv;                                                         \
      }                                                                      \
      uint2 w; w.x = pack2(v.x, v.y); w.y = pack2(v.z, v.w);                 \
      int off = (row * 128 + cg * 8) ^ ((row & 7) << 4);                     \
      *(uint2*)(&sA[buf][off]) = w;                                          \
    }                                                                        \
  }

  STAGE_B(0, 0);
  STAGE_A(0, 0);
  __syncthreads();

  #pragma unroll
  for (int c = 0; c < NCHUNK; ++c){
    const int cur = c & 1;
    if (c + 1 < NCHUNK){
      STAGE_B(c + 1, cur ^ 1);
      STAGE_A(c + 1, cur ^ 1);
    }
    #pragma unroll
    for (int ks = 0; ks < 2; ++ks){
      const int kb = (ks * 32 + khi * 8) * 2;
      s16x8 af[2], bfr[4];
      #pragma unroll
      for (int mi = 0; mi < 2; ++mi){
        int row = wm * 32 + mi * 16 + rlo;
        af[mi] = *(const s16x8*)(&sA[cur][(row * 128 + kb) ^ ((row & 7) << 4)]);
      }
      #pragma unroll
      for (int ni = 0; ni < 4; ++ni){
        int col = wn * 64 + ni * 16 + rlo;
        bfr[ni] = *(const s16x8*)(&sB[cur][(col * 128 + kb) ^ ((col & 7) << 4)]);
      }
      #pragma unroll
      for (int mi = 0; mi < 2; ++mi)
        #pragma unroll
        for (int ni = 0; ni < 4; ++ni)
          acc[mi][ni] = __builtin_amdgcn_mfma_f32_16x16x32_bf16(
              af[mi], bfr[ni], acc[mi][ni], 0, 0, 0);
    }
    __syncthreads();
  }

  // Epilogue: scatter (+bias) to agg[dst]
  const float* bias = dir ? bias_b : bias_f;
  #pragma unroll
  for (int ni = 0; ni < 4; ++ni){
    const int gcol = wn * 64 + ni * 16 + rlo;
    const float bv = bias[gcol];
    #pragma unroll
    for (int mi = 0; mi < 2; ++mi){
      #pragma unroll
      for (int r = 0; r < 4; ++r){
        int m = wm * 32 + mi * 16 + khi * 4 + r;
        long e = e0 + m;
        if (e < n_edges){
          int dst = dir ? sIdx[0][m] : sIdx[1][m];
          atomicAdd(agg + (long)dst * D + gcol, acc[mi][ni][r] + bv);
        }
      }
    }
  }
  #undef STAGE_A
  #undef STAGE_B
}

__global__ __launch_bounds__(256) void finish(
    const float* __restrict__ agg, const float* __restrict__ cnt,
    const float* __restrict__ H, const float* __restrict__ gamma,
    const float* __restrict__ beta, float* __restrict__ out)
{
  const int n = blockIdx.x;
  const int j = threadIdx.x;
  float c = cnt[n]; c = c < 1.f ? 1.f : c;
  float a = agg[(long)n * D + j] / c;
  float x = (a > 0.f ? a : LEAKY * a) + H[(long)n * D + j];
  float s1 = x, s2 = x * x;
  #pragma unroll
  for (int off = 32; off > 0; off >>= 1){
    s1 += __shfl_xor(s1, off);
    s2 += __shfl_xor(s2, off);
  }
  __shared__ float rs[8];
  if ((j & 63) == 0){ rs[j >> 6] = s1; rs[4 + (j >> 6)] = s2; }
  __syncthreads();
  float t1 = rs[0] + rs[1] + rs[2] + rs[3];
  float t2 = rs[4] + rs[5] + rs[6] + rs[7];
  float mu = t1 * (1.f / D);
  float var = t2 * (1.f / D) - mu * mu;
  float r = rsqrtf(var + EPS);
  out[(long)n * D + j] = (x - mu) * r * gamma[j] + beta[j];
}

extern "C" void kernel_launch(void* const* d_in, const int* in_sizes, int n_in,
                              void* d_out, int out_size, void* d_ws, size_t ws_size,
                              hipStream_t stream)
{
  const float* H      = (const float*)d_in[0];
  const float* E      = (const float*)d_in[1];
  const int*   ht     = (const int*)d_in[2];
  const float* W_fwd  = (const float*)d_in[3];
  const float* b_fwd  = (const float*)d_in[4];
  const float* W_back = (const float*)d_in[5];
  const float* b_back = (const float*)d_in[6];
  const float* gamma  = (const float*)d_in[7];
  const float* beta   = (const float*)d_in[8];
  float* out = (float*)d_out;

  const int n_nodes = in_sizes[0] / D;
  const int n_edges = in_sizes[2] / 2;

  float* agg = (float*)d_ws;
  float* cnt = agg + (size_t)n_nodes * D;
  size_t woff = ((size_t)n_nodes * D + n_nodes) * sizeof(float);
  woff = (woff + 255) & ~(size_t)255;
  unsigned short* Wimg = (unsigned short*)((char*)d_ws + woff);

  hipMemsetAsync(d_ws, 0, ((size_t)n_nodes * D + n_nodes) * sizeof(float), stream);
  prep_w<<<(2 * NCHUNK * D * BK) / 256, 256, 0, stream>>>(W_fwd, W_back, Wimg);
  count_deg<<<(n_edges + 255) / 256, 256, 0, stream>>>(ht, cnt, n_edges);

  const int ntiles = (n_edges + TE - 1) / TE;
  edge_gemm<<<ntiles * 2, 1024, 0, stream>>>(H, E, ht, b_fwd, b_back, Wimg, agg, n_edges);
  finish<<<n_nodes, 256, 0, stream>>>(agg, cnt, H, gamma, beta, out);
}

// Round 4
// 661.171 us; speedup vs baseline: 1.9649x; 1.0755x over previous
//
#include <hip/hip_runtime.h>
#include <hip/hip_bf16.h>

#define D 256
#define TE 128         // edges per tile
#define NB 128         // output cols per block (colhalf)
#define BK 64          // K-chunk
#define NCHUNK 12      // 4 groups x [E | E*H | H]
#define LEAKY 0.01f
#define EPS 1e-5f

typedef float f32x4 __attribute__((ext_vector_type(4)));
typedef short s16x8 __attribute__((ext_vector_type(8)));

#define GLL16(g, l) __builtin_amdgcn_global_load_lds(                      \
    (const __attribute__((address_space(1))) unsigned int*)(g),            \
    (__attribute__((address_space(3))) unsigned int*)(l), 16, 0, 0)

__device__ __forceinline__ unsigned short f2bf(float f){
  union { float f; unsigned int u; } v; v.f = f;
  unsigned int u = v.u;
  return (unsigned short)((u + 0x7fffu + ((u >> 16) & 1u)) >> 16);
}
__device__ __forceinline__ unsigned int pack2(float a, float b){
  return (unsigned int)f2bf(a) | ((unsigned int)f2bf(b) << 16);
}

// Pre-swizzled LDS images of folded weights, per (dir, colhalf, chunk).
// K reorder: group g in 0..3, parts [E_g | (E*H)_g | H_g], chunk c = g*3+part.
// Image tile t = (dir*2+h)*12 + c (16 KB): boff = (j*128 + k*2) ^ ((j&7)<<4),
// j = col within half (0..127), k = local K (0..63).
__global__ void prep_w(const float* __restrict__ Wf, const float* __restrict__ Wb,
                       unsigned short* __restrict__ Wimg)
{
  int i = blockIdx.x * 256 + threadIdx.x;       // 2*2*12*128*64 = 393216
  int inner = i & 8191;                         // j*64 + k
  int t = i >> 13;                              // (dir*2+h)*12 + c
  int c = t % 12;
  int q = t / 12;
  int dir = q >> 1, h = q & 1;
  int g = c / 3, part = c - g * 3;
  int j = inner >> 6, k = inner & 63;
  int x = g * 64 + k;                           // original feature index
  const float* row = (dir ? Wb : Wf) + (long)(h * NB + j) * (4 * D);
  // raw = [Hh | E | Hh+E | Hh*E]:
  float v;
  if (part == 0)      v = row[256 + x] + row[512 + x];   // E coeff
  else if (part == 1) v = row[768 + x];                  // Hh*E coeff
  else                v = row[x] + row[512 + x];         // Hh coeff
  int boff = (j * 128 + k * 2) ^ ((j & 7) << 4);
  *(unsigned short*)((char*)Wimg + (size_t)t * 16384 + boff) = f2bf(v);
}

__global__ void count_deg(const int* __restrict__ ht, float* __restrict__ cnt, int n_edges)
{
  int e = blockIdx.x * 256 + threadIdx.x;
  if (e < n_edges){
    atomicAdd(&cnt[ht[2*e]],   1.0f);
    atomicAdd(&cnt[ht[2*e+1]], 1.0f);
  }
}

__global__ __launch_bounds__(512, 4) void edge_gemm(
    const float* __restrict__ H, const float* __restrict__ E,
    const int* __restrict__ ht, const float* __restrict__ bias_f,
    const float* __restrict__ bias_b, const unsigned short* __restrict__ Wimg,
    float* __restrict__ agg, int n_edges)
{
  __shared__ char sA[2][16384];   // 128 rows x 64 k
  __shared__ char sB[2][16384];   // 128 cols x 64 k
  __shared__ int sIdx[2][TE];

  // Bijective XCD-chunked swizzle: 4 q-blocks of a tile land L-consecutive
  // on the same XCD (nwg % 8 handled via m204 variant).
  const int nwg  = gridDim.x;
  const int orig = blockIdx.x;
  const int xcd  = orig & 7;
  const int lq = nwg >> 3, lr = nwg & 7;
  const int L = (xcd < lr ? xcd * (lq + 1) : lr * (lq + 1) + (xcd - lr) * lq)
                + (orig >> 3);
  const long e0 = (long)(L >> 2) * TE;
  const int dir = (L >> 1) & 1;
  const int h   = L & 1;

  const int tid  = threadIdx.x;
  const int lane = tid & 63;
  const int wave = tid >> 6;      // 0..7

  if (tid < TE){
    long e = e0 + tid; if (e >= n_edges) e = n_edges - 1;
    sIdx[0][tid] = ht[2*e]; sIdx[1][tid] = ht[2*e+1];
  }
  __syncthreads();

  // A staging: thread -> 4 rows x 4 cols. cg = col group, rows rg*4+i.
  const int cg = tid & 15;
  const int rg = tid >> 4;        // 0..31
  const float* eptr[4]; const float* hptr[4];
  #pragma unroll
  for (int i = 0; i < 4; ++i){
    int row = rg * 4 + i;
    long e = e0 + row; if (e >= n_edges) e = n_edges - 1;
    eptr[i] = E + e * D;
    hptr[i] = H + (long)sIdx[dir][row] * D;  // dir0: H[head], dir1: H[tail]
  }
  const char* wq = (const char*)Wimg + (size_t)(dir * 2 + h) * NCHUNK * 16384;

  f32x4 acc[4][2];
  #pragma unroll
  for (int mi = 0; mi < 4; ++mi)
    #pragma unroll
    for (int ni = 0; ni < 2; ++ni)
      acc[mi][ni] = (f32x4){0.f, 0.f, 0.f, 0.f};

  float4 Ev[4];

  const int rlo = lane & 15;
  const int khi = lane >> 4;
  const int wm = wave >> 2;       // 0..1: 64-row slab
  const int wn = wave & 3;        // 0..3: 32-col slab

  #define STAGE_B(c, buf) {                                                  \
    const char* srcb = wq + (size_t)(c) * 16384 + wave * 2048 + lane * 16;   \
    char* db = &sB[buf][wave * 2048];                                        \
    GLL16(srcb,        db);                                                  \
    GLL16(srcb + 1024, db + 1024);                                           \
  }

  #define STAGE_A(c, buf) {                                                  \
    const int g = (c) / 3, part = (c) - g * 3;                               \
    _Pragma("unroll")                                                        \
    for (int i = 0; i < 4; ++i){                                             \
      int row = rg * 4 + i;                                                  \
      float4 v;                                                              \
      if (part == 0){                                                        \
        Ev[i] = *(const float4*)(eptr[i] + g * 64 + cg * 4);                 \
        v = Ev[i];                                                           \
      } else {                                                               \
        float4 hv = *(const float4*)(hptr[i] + g * 64 + cg * 4);             \
        if (part == 1) v = make_float4(Ev[i].x*hv.x, Ev[i].y*hv.y,           \
                                       Ev[i].z*hv.z, Ev[i].w*hv.w);          \
        else v = hv;                                                         \
      }                                                                      \
      uint2 w; w.x = pack2(v.x, v.y); w.y = pack2(v.z, v.w);                 \
      int off = (row * 128 + cg * 8) ^ ((row & 7) << 4);                     \
      *(uint2*)(&sA[buf][off]) = w;                                          \
    }                                                                        \
  }

  STAGE_B(0, 0);
  STAGE_A(0, 0);
  __syncthreads();

  #pragma unroll
  for (int c = 0; c < NCHUNK; ++c){
    const int cur = c & 1;
    if (c + 1 < NCHUNK){
      STAGE_B(c + 1, cur ^ 1);
      STAGE_A(c + 1, cur ^ 1);
    }
    #pragma unroll
    for (int ks = 0; ks < 2; ++ks){
      const int kb = (ks * 32 + khi * 8) * 2;
      s16x8 af[4], bfr[2];
      #pragma unroll
      for (int mi = 0; mi < 4; ++mi){
        int row = wm * 64 + mi * 16 + rlo;
        af[mi] = *(const s16x8*)(&sA[cur][(row * 128 + kb) ^ ((row & 7) << 4)]);
      }
      #pragma unroll
      for (int ni = 0; ni < 2; ++ni){
        int col = wn * 32 + ni * 16 + rlo;
        bfr[ni] = *(const s16x8*)(&sB[cur][(col * 128 + kb) ^ ((col & 7) << 4)]);
      }
      #pragma unroll
      for (int mi = 0; mi < 4; ++mi)
        #pragma unroll
        for (int ni = 0; ni < 2; ++ni)
          acc[mi][ni] = __builtin_amdgcn_mfma_f32_16x16x32_bf16(
              af[mi], bfr[ni], acc[mi][ni], 0, 0, 0);
    }
    __syncthreads();
  }

  // Epilogue: scatter (+bias) to agg[dst]
  const float* bias = dir ? bias_b : bias_f;
  #pragma unroll
  for (int ni = 0; ni < 2; ++ni){
    const int gcol = h * NB + wn * 32 + ni * 16 + rlo;
    const float bv = bias[gcol];
    #pragma unroll
    for (int mi = 0; mi < 4; ++mi){
      #pragma unroll
      for (int r = 0; r < 4; ++r){
        int m = wm * 64 + mi * 16 + khi * 4 + r;
        long e = e0 + m;
        if (e < n_edges){
          int dst = dir ? sIdx[0][m] : sIdx[1][m];
          atomicAdd(agg + (long)dst * D + gcol, acc[mi][ni][r] + bv);
        }
      }
    }
  }
  #undef STAGE_A
  #undef STAGE_B
}

__global__ __launch_bounds__(256) void finish(
    const float* __restrict__ agg, const float* __restrict__ cnt,
    const float* __restrict__ H, const float* __restrict__ gamma,
    const float* __restrict__ beta, float* __restrict__ out)
{
  const int n = blockIdx.x;
  const int j = threadIdx.x;
  float c = cnt[n]; c = c < 1.f ? 1.f : c;
  float a = agg[(long)n * D + j] / c;
  float x = (a > 0.f ? a : LEAKY * a) + H[(long)n * D + j];
  float s1 = x, s2 = x * x;
  #pragma unroll
  for (int off = 32; off > 0; off >>= 1){
    s1 += __shfl_xor(s1, off);
    s2 += __shfl_xor(s2, off);
  }
  __shared__ float rs[8];
  if ((j & 63) == 0){ rs[j >> 6] = s1; rs[4 + (j >> 6)] = s2; }
  __syncthreads();
  float t1 = rs[0] + rs[1] + rs[2] + rs[3];
  float t2 = rs[4] + rs[5] + rs[6] + rs[7];
  float mu = t1 * (1.f / D);
  float var = t2 * (1.f / D) - mu * mu;
  float r = rsqrtf(var + EPS);
  out[(long)n * D + j] = (x - mu) * r * gamma[j] + beta[j];
}

extern "C" void kernel_launch(void* const* d_in, const int* in_sizes, int n_in,
                              void* d_out, int out_size, void* d_ws, size_t ws_size,
                              hipStream_t stream)
{
  const float* H      = (const float*)d_in[0];
  const float* E      = (const float*)d_in[1];
  const int*   ht     = (const int*)d_in[2];
  const float* W_fwd  = (const float*)d_in[3];
  const float* b_fwd  = (const float*)d_in[4];
  const float* W_back = (const float*)d_in[5];
  const float* b_back = (const float*)d_in[6];
  const float* gamma  = (const float*)d_in[7];
  const float* beta   = (const float*)d_in[8];
  float* out = (float*)d_out;

  const int n_nodes = in_sizes[0] / D;
  const int n_edges = in_sizes[2] / 2;

  float* agg = (float*)d_ws;
  float* cnt = agg + (size_t)n_nodes * D;
  size_t woff = ((size_t)n_nodes * D + n_nodes) * sizeof(float);
  woff = (woff + 255) & ~(size_t)255;
  unsigned short* Wimg = (unsigned short*)((char*)d_ws + woff);

  hipMemsetAsync(d_ws, 0, ((size_t)n_nodes * D + n_nodes) * sizeof(float), stream);
  prep_w<<<(2 * 2 * NCHUNK * NB * BK) / 256, 256, 0, stream>>>(W_fwd, W_back, Wimg);
  count_deg<<<(n_edges + 255) / 256, 256, 0, stream>>>(ht, cnt, n_edges);

  const int ntiles = (n_edges + TE - 1) / TE;
  edge_gemm<<<ntiles * 4, 512, 0, stream>>>(H, E, ht, b_fwd, b_back, Wimg, agg, n_edges);
  finish<<<n_nodes, 256, 0, stream>>>(agg, cnt, H, gamma, beta, out);
}

// Round 6
// 660.405 us; speedup vs baseline: 1.9672x; 1.0012x over previous
//
#include <hip/hip_runtime.h>
#include <hip/hip_bf16.h>

#define D 256
#define TE 128         // edges per tile
#define NB 128         // output cols per block (colhalf)
#define BK 64          // K-chunk
#define NCHUNK 12      // 4 groups x [E | E*H | H]
#define LEAKY 0.01f
#define EPS 1e-5f

typedef float f32x4 __attribute__((ext_vector_type(4)));
typedef short s16x8 __attribute__((ext_vector_type(8)));

#define GLL16(g, l) __builtin_amdgcn_global_load_lds(                      \
    (const __attribute__((address_space(1))) unsigned int*)(g),            \
    (__attribute__((address_space(3))) unsigned int*)(l), 16, 0, 0)

__device__ __forceinline__ unsigned short f2bf(float f){
  union { float f; unsigned int u; } v; v.f = f;
  unsigned int u = v.u;
  return (unsigned short)((u + 0x7fffu + ((u >> 16) & 1u)) >> 16);
}
__device__ __forceinline__ unsigned int pack2(float a, float b){
  return (unsigned int)f2bf(a) | ((unsigned int)f2bf(b) << 16);
}

// Pre-swizzled LDS images of folded weights, per (dir, colhalf, chunk).
// K reorder: group g in 0..3, parts [E_g | (E*H)_g | H_g], chunk c = g*3+part.
// Image tile t = (dir*2+h)*12 + c (16 KB): boff = (j*128 + k*2) ^ ((j&7)<<4).
__global__ void prep_w(const float* __restrict__ Wf, const float* __restrict__ Wb,
                       unsigned short* __restrict__ Wimg)
{
  int i = blockIdx.x * 256 + threadIdx.x;       // 2*2*12*128*64 = 393216
  int inner = i & 8191;                         // j*64 + k
  int t = i >> 13;                              // (dir*2+h)*12 + c
  int c = t % 12;
  int q = t / 12;
  int dir = q >> 1, h = q & 1;
  int g = c / 3, part = c - g * 3;
  int j = inner >> 6, k = inner & 63;
  int x = g * 64 + k;                           // original feature index
  const float* row = (dir ? Wb : Wf) + (long)(h * NB + j) * (4 * D);
  // raw = [Hh | E | Hh+E | Hh*E]:
  float v;
  if (part == 0)      v = row[256 + x] + row[512 + x];   // E coeff
  else if (part == 1) v = row[768 + x];                  // Hh*E coeff
  else                v = row[x] + row[512 + x];         // Hh coeff
  int boff = (j * 128 + k * 2) ^ ((j & 7) << 4);
  *(unsigned short*)((char*)Wimg + (size_t)t * 16384 + boff) = f2bf(v);
}

__global__ void count_deg(const int* __restrict__ ht, float* __restrict__ cnt, int n_edges)
{
  int e = blockIdx.x * 256 + threadIdx.x;
  if (e < n_edges){
    atomicAdd(&cnt[ht[2*e]],   1.0f);
    atomicAdd(&cnt[ht[2*e+1]], 1.0f);
  }
}

__global__ __launch_bounds__(512, 4) void edge_gemm(
    const float* __restrict__ H, const float* __restrict__ E,
    const int* __restrict__ ht, const float* __restrict__ bias_f,
    const float* __restrict__ bias_b, const unsigned short* __restrict__ Wimg,
    float* __restrict__ agg, int n_edges)
{
  __shared__ char sAl[2][16384];  // 128 rows x 64 k
  __shared__ char sBl[2][16384];  // 128 cols x 64 k
  __shared__ int sIdx[2][TE];

  // Bijective XCD-chunked swizzle: 4 q-blocks of a tile on the same XCD.
  const int nwg  = gridDim.x;
  const int orig = blockIdx.x;
  const int xcd  = orig & 7;
  const int lq = nwg >> 3, lr = nwg & 7;
  const int L = (xcd < lr ? xcd * (lq + 1) : lr * (lq + 1) + (xcd - lr) * lq)
                + (orig >> 3);
  const long e0 = (long)(L >> 2) * TE;
  const int dir = (L >> 1) & 1;
  const int h   = L & 1;

  const int tid  = threadIdx.x;
  const int lane = tid & 63;
  const int wave = tid >> 6;      // 0..7

  if (tid < TE){
    long e = e0 + tid; if (e >= n_edges) e = n_edges - 1;
    sIdx[0][tid] = ht[2*e]; sIdx[1][tid] = ht[2*e+1];
  }
  __syncthreads();

  // A staging: thread -> 4 rows x 4 cols. cg = col group, rows rg*4+i.
  const int cg = tid & 15;
  const int rg = tid >> 4;        // 0..31
  const float* eptr[4]; const float* hptr[4];
  #pragma unroll
  for (int i = 0; i < 4; ++i){
    int row = rg * 4 + i;
    long e = e0 + row; if (e >= n_edges) e = n_edges - 1;
    eptr[i] = E + e * D;
    hptr[i] = H + (long)sIdx[dir][row] * D;  // dir0: H[head], dir1: H[tail]
  }
  const char* wq = (const char*)Wimg + (size_t)(dir * 2 + h) * NCHUNK * 16384;

  f32x4 acc[4][2];
  #pragma unroll
  for (int mi = 0; mi < 4; ++mi)
    #pragma unroll
    for (int ni = 0; ni < 2; ++ni)
      acc[mi][ni] = (f32x4){0.f, 0.f, 0.f, 0.f};

  float4 sl0[4], sl1[4];          // A reg slots: A(x) -> slot (x&1)
  float4 Ev[4];                   // persistent E regs across a part-triplet

  const int rlo = lane & 15;
  const int khi = lane >> 4;
  const int wm = wave >> 2;       // 0..1: 64-row slab
  const int wn = wave & 3;        // 0..3: 32-col slab

  // Issue A-loads for chunk c into reg slot (c&1). part: 0=E, else H.
  // Loads land a full iteration before their pack/ds_write, so the
  // __syncthreads vmcnt(0) drain finds them complete (T14, safe form).
  #define ISSUE_A(c) {                                                       \
    const int g_ = (c) / 3, part_ = (c) % 3;                                 \
    float4* dst_ = ((c) & 1) ? sl1 : sl0;                                    \
    _Pragma("unroll")                                                        \
    for (int i = 0; i < 4; ++i)                                              \
      dst_[i] = *(const float4*)((part_ == 0 ? eptr[i] : hptr[i])            \
                                 + g_ * 64 + cg * 4);                        \
  }

  // ds_write chunk c from its reg slot into LDS buf.
  #define WRITE_A(c, buf) {                                                  \
    const int part_ = (c) % 3;                                               \
    float4* src_ = ((c) & 1) ? sl1 : sl0;                                    \
    _Pragma("unroll")                                                        \
    for (int i = 0; i < 4; ++i){                                             \
      int row = rg * 4 + i;                                                  \
      float4 v;                                                              \
      if (part_ == 0){ Ev[i] = src_[i]; v = src_[i]; }                       \
      else if (part_ == 1) v = make_float4(Ev[i].x*src_[i].x,                \
          Ev[i].y*src_[i].y, Ev[i].z*src_[i].z, Ev[i].w*src_[i].w);          \
      else v = src_[i];                                                      \
      uint2 w; w.x = pack2(v.x, v.y); w.y = pack2(v.z, v.w);                 \
      int off = (row * 128 + cg * 8) ^ ((row & 7) << 4);                     \
      *(uint2*)(&sAl[buf][off]) = w;                                         \
    }                                                                        \
  }

  #define STAGE_B(c, buf) {                                                  \
    const char* srcb = wq + (size_t)(c) * 16384 + wave * 2048 + lane * 16;   \
    char* db = &sBl[buf][wave * 2048];                                       \
    GLL16(srcb,        db);                                                  \
    GLL16(srcb + 1024, db + 1024);                                           \
  }

  // ---- Prologue: fill slots for chunks 0,1; stage chunk 0; issue 2 ahead.
  ISSUE_A(0);
  ISSUE_A(1);
  STAGE_B(0, 0);
  WRITE_A(0, 0);
  ISSUE_A(2);
  __syncthreads();

  // ---- Main loop. Top-of-iter invariant: buf[c&1] ready; A(c+1) in regs;
  // slots hold A(c+1), A(c+2).
  #pragma unroll
  for (int c = 0; c < NCHUNK; ++c){
    const int cur = c & 1;
    if (c + 1 < NCHUNK){
      STAGE_B(c + 1, cur ^ 1);     // glds -> other buf (in flight over MFMA)
      WRITE_A(c + 1, cur ^ 1);     // regs (arrived last iter) -> other buf
    }
    if (c + 3 < NCHUNK){
      ISSUE_A(c + 3);              // into slot just freed by WRITE_A
    }
    #pragma unroll
    for (int ks = 0; ks < 2; ++ks){
      const int kb = (ks * 32 + khi * 8) * 2;
      s16x8 af[4], bfr[2];
      #pragma unroll
      for (int mi = 0; mi < 4; ++mi){
        int row = wm * 64 + mi * 16 + rlo;
        af[mi] = *(const s16x8*)(&sAl[cur][(row * 128 + kb) ^ ((row & 7) << 4)]);
      }
      #pragma unroll
      for (int ni = 0; ni < 2; ++ni){
        int col = wn * 32 + ni * 16 + rlo;
        bfr[ni] = *(const s16x8*)(&sBl[cur][(col * 128 + kb) ^ ((col & 7) << 4)]);
      }
      #pragma unroll
      for (int mi = 0; mi < 4; ++mi)
        #pragma unroll
        for (int ni = 0; ni < 2; ++ni)
          acc[mi][ni] = __builtin_amdgcn_mfma_f32_16x16x32_bf16(
              af[mi], bfr[ni], acc[mi][ni], 0, 0, 0);
    }
    if (c + 1 < NCHUNK) __syncthreads();
  }

  // Epilogue: scatter (+bias) to agg[dst]
  const float* bias = dir ? bias_b : bias_f;
  #pragma unroll
  for (int ni = 0; ni < 2; ++ni){
    const int gcol = h * NB + wn * 32 + ni * 16 + rlo;
    const float bv = bias[gcol];
    #pragma unroll
    for (int mi = 0; mi < 4; ++mi){
      #pragma unroll
      for (int r = 0; r < 4; ++r){
        int m = wm * 64 + mi * 16 + khi * 4 + r;
        long e = e0 + m;
        if (e < n_edges){
          int dst = dir ? sIdx[0][m] : sIdx[1][m];
          atomicAdd(agg + (long)dst * D + gcol, acc[mi][ni][r] + bv);
        }
      }
    }
  }
  #undef ISSUE_A
  #undef WRITE_A
  #undef STAGE_B
}

__global__ __launch_bounds__(256) void finish(
    const float* __restrict__ agg, const float* __restrict__ cnt,
    const float* __restrict__ H, const float* __restrict__ gamma,
    const float* __restrict__ beta, float* __restrict__ out)
{
  const int n = blockIdx.x;
  const int j = threadIdx.x;
  float c = cnt[n]; c = c < 1.f ? 1.f : c;
  float a = agg[(long)n * D + j] / c;
  float x = (a > 0.f ? a : LEAKY * a) + H[(long)n * D + j];
  float s1 = x, s2 = x * x;
  #pragma unroll
  for (int off = 32; off > 0; off >>= 1){
    s1 += __shfl_xor(s1, off);
    s2 += __shfl_xor(s2, off);
  }
  __shared__ float rs[8];
  if ((j & 63) == 0){ rs[j >> 6] = s1; rs[4 + (j >> 6)] = s2; }
  __syncthreads();
  float t1 = rs[0] + rs[1] + rs[2] + rs[3];
  float t2 = rs[4] + rs[5] + rs[6] + rs[7];
  float mu = t1 * (1.f / D);
  float var = t2 * (1.f / D) - mu * mu;
  float r = rsqrtf(var + EPS);
  out[(long)n * D + j] = (x - mu) * r * gamma[j] + beta[j];
}

extern "C" void kernel_launch(void* const* d_in, const int* in_sizes, int n_in,
                              void* d_out, int out_size, void* d_ws, size_t ws_size,
                              hipStream_t stream)
{
  const float* H      = (const float*)d_in[0];
  const float* E      = (const float*)d_in[1];
  const int*   ht     = (const int*)d_in[2];
  const float* W_fwd  = (const float*)d_in[3];
  const float* b_fwd  = (const float*)d_in[4];
  const float* W_back = (const float*)d_in[5];
  const float* b_back = (const float*)d_in[6];
  const float* gamma  = (const float*)d_in[7];
  const float* beta   = (const float*)d_in[8];
  float* out = (float*)d_out;

  const int n_nodes = in_sizes[0] / D;
  const int n_edges = in_sizes[2] / 2;

  float* agg = (float*)d_ws;
  float* cnt = agg + (size_t)n_nodes * D;
  size_t woff = ((size_t)n_nodes * D + n_nodes) * sizeof(float);
  woff = (woff + 255) & ~(size_t)255;
  unsigned short* Wimg = (unsigned short*)((char*)d_ws + woff);

  hipMemsetAsync(d_ws, 0, ((size_t)n_nodes * D + n_nodes) * sizeof(float), stream);
  prep_w<<<(2 * 2 * NCHUNK * NB * BK) / 256, 256, 0, stream>>>(W_fwd, W_back, Wimg);
  count_deg<<<(n_edges + 255) / 256, 256, 0, stream>>>(ht, cnt, n_edges);

  const int ntiles = (n_edges + TE - 1) / TE;
  edge_gemm<<<ntiles * 4, 512, 0, stream>>>(H, E, ht, b_fwd, b_back, Wimg, agg, n_edges);
  finish<<<n_nodes, 256, 0, stream>>>(agg, cnt, H, gamma, beta, out);
}

// Round 7
// 526.001 us; speedup vs baseline: 2.4699x; 1.2555x over previous
//
#include <hip/hip_runtime.h>
#include <hip/hip_bf16.h>

#define D 256
#define TE 128         // messages per tile
#define NB 128         // output cols per block (colhalf)
#define BK 64          // K-chunk
#define NCHUNK 12      // 4 groups x [E | E*H | H]
#define LEAKY 0.01f
#define EPS 1e-5f

typedef float f32x4 __attribute__((ext_vector_type(4)));
typedef short s16x8 __attribute__((ext_vector_type(8)));

#define GLL16(g, l) __builtin_amdgcn_global_load_lds(                      \
    (const __attribute__((address_space(1))) unsigned int*)(g),            \
    (__attribute__((address_space(3))) unsigned int*)(l), 16, 0, 0)

__device__ __forceinline__ unsigned short f2bf(float f){
  union { float f; unsigned int u; } v; v.f = f;
  unsigned int u = v.u;
  return (unsigned short)((u + 0x7fffu + ((u >> 16) & 1u)) >> 16);
}
__device__ __forceinline__ unsigned int pack2(float a, float b){
  return (unsigned int)f2bf(a) | ((unsigned int)f2bf(b) << 16);
}

// Pre-swizzled LDS images of folded weights, per (dir, colhalf, chunk).
// K reorder: group g in 0..3, parts [E_g | (E*H)_g | H_g], chunk c = g*3+part.
// Image tile t = (dir*2+h)*12 + c (16 KB): boff = (j*128 + k*2) ^ ((j&7)<<4).
__global__ void prep_w(const float* __restrict__ Wf, const float* __restrict__ Wb,
                       unsigned short* __restrict__ Wimg)
{
  int i = blockIdx.x * 256 + threadIdx.x;       // 2*2*12*128*64 = 393216
  int inner = i & 8191;                         // j*64 + k
  int t = i >> 13;                              // (dir*2+h)*12 + c
  int c = t % 12;
  int q = t / 12;
  int dir = q >> 1, h = q & 1;
  int g = c / 3, part = c - g * 3;
  int j = inner >> 6, k = inner & 63;
  int x = g * 64 + k;                           // original feature index
  const float* row = (dir ? Wb : Wf) + (long)(h * NB + j) * (4 * D);
  // raw = [Hh | E | Hh+E | Hh*E]:
  float v;
  if (part == 0)      v = row[256 + x] + row[512 + x];   // E coeff
  else if (part == 1) v = row[768 + x];                  // Hh*E coeff
  else                v = row[x] + row[512 + x];         // Hh coeff
  int boff = (j * 128 + k * 2) ^ ((j & 7) << 4);
  *(unsigned short*)((char*)Wimg + (size_t)t * 16384 + boff) = f2bf(v);
}

// Per-dir dst histogram: cnt[0..n) = fwd (dst=tail), cnt[n..2n) = back (dst=head)
__global__ void count2(const int* __restrict__ ht, int* __restrict__ cnt,
                       int n_edges, int n_nodes)
{
  int e = blockIdx.x * 256 + threadIdx.x;
  if (e < n_edges){
    atomicAdd(&cnt[ht[2*e+1]], 1);
    atomicAdd(&cnt[n_nodes + ht[2*e]], 1);
  }
}

__global__ void scan_sums(const int* __restrict__ cnt, int* __restrict__ bsum, int N2)
{
  int t = threadIdx.x, b = blockIdx.x;
  int i = b * 1024 + t;
  int v = (i < N2) ? cnt[i] : 0;
  #pragma unroll
  for (int o = 32; o > 0; o >>= 1) v += __shfl_down(v, o);
  __shared__ int red[16];
  int lane = t & 63, wv = t >> 6;
  if (lane == 0) red[wv] = v;
  __syncthreads();
  if (t == 0){ int s = 0; for (int k = 0; k < 16; ++k) s += red[k]; bsum[b] = s; }
}

__global__ void scan_bases(const int* __restrict__ bsum, int* __restrict__ bases, int nb)
{
  if (threadIdx.x == 0 && blockIdx.x == 0){
    int a = 0;
    for (int k = 0; k < nb; ++k){ bases[k] = a; a += bsum[k]; }
  }
}

__global__ void scan_off(const int* __restrict__ cnt, const int* __restrict__ bases,
                         int* __restrict__ off, int N2)
{
  int t = threadIdx.x, b = blockIdx.x;
  int i = b * 1024 + t;
  int v = (i < N2) ? cnt[i] : 0;
  int lane = t & 63, wv = t >> 6;
  int x = v;
  #pragma unroll
  for (int o = 1; o < 64; o <<= 1){ int y = __shfl_up(x, o); if (lane >= o) x += y; }
  __shared__ int ws[16];
  if (lane == 63) ws[wv] = x;
  __syncthreads();
  if (t == 0){ int a = 0; for (int k = 0; k < 16; ++k){ int tmp = ws[k]; ws[k] = a; a += tmp; } }
  __syncthreads();
  if (i < N2) off[i] = bases[b] + ws[wv] + x - v;
}

// Build dst-sorted lists: positions [0,NE) = fwd sorted by tail, [NE,2NE) = back by head.
__global__ void scatter_msgs(const int* __restrict__ ht, const int* __restrict__ off,
                             int* __restrict__ cursor, int* __restrict__ perm,
                             int* __restrict__ dstS, int* __restrict__ hS,
                             int n_edges, int n_nodes)
{
  int m = blockIdx.x * 256 + threadIdx.x;
  if (m >= 2 * n_edges) return;
  int e  = (m < n_edges) ? m : m - n_edges;
  int hd = ht[2*e], tl = ht[2*e+1];
  int dst = (m < n_edges) ? tl : hd;
  int oth = (m < n_edges) ? hd : tl;
  int idx = ((m < n_edges) ? 0 : n_nodes) + dst;
  int pos = off[idx] + atomicAdd(&cursor[idx], 1);
  perm[pos] = e; dstS[pos] = dst; hS[pos] = oth;
}

__global__ __launch_bounds__(512, 4) void edge_gemm(
    const float* __restrict__ H, const float* __restrict__ E,
    const int* __restrict__ perm, const int* __restrict__ dstS,
    const int* __restrict__ hS, const unsigned short* __restrict__ Wimg,
    float* __restrict__ agg, int n_edges, int n_nodes)
{
  __shared__ char smem[65536];     // A dbuf (0..32K) + B dbuf (32K..64K); C reuse
  __shared__ int sDst[TE];
  char (*sAl)[16384] = (char(*)[16384])smem;
  char (*sBl)[16384] = (char(*)[16384])(smem + 32768);

  // Bijective XCD-chunked swizzle: 4 q-blocks of a tile on the same XCD.
  const int nwg  = gridDim.x;
  const int orig = blockIdx.x;
  const int xcd  = orig & 7;
  const int lq = nwg >> 3, lr = nwg & 7;
  const int L = (xcd < lr ? xcd * (lq + 1) : lr * (lq + 1) + (xcd - lr) * lq)
                + (orig >> 3);
  const int tile = L >> 2;
  const int dir  = (L >> 1) & 1;
  const int h    = L & 1;
  const int pos0 = tile * TE;      // within dir-list

  const int tid  = threadIdx.x;
  const int lane = tid & 63;
  const int wave = tid >> 6;      // 0..7

  // A staging: thread -> 4 rows x 4 cols. cg = col group, rows rg*4+i.
  const int cg = tid & 15;
  const int rg = tid >> 4;        // 0..31
  const float* eptr[4]; const float* hptr[4];
  #pragma unroll
  for (int i = 0; i < 4; ++i){
    int row = rg * 4 + i;
    int rp  = pos0 + row;
    bool pad = (rp >= n_edges);
    int gpos = dir * n_edges + (pad ? (n_edges - 1) : rp);
    eptr[i] = E + (long)perm[gpos] * D;
    hptr[i] = H + (long)hS[gpos] * D;
    if (cg == 0) sDst[row] = pad ? 0x7fffffff : dstS[gpos];
  }
  __syncthreads();

  const char* wq = (const char*)Wimg + (size_t)(dir * 2 + h) * NCHUNK * 16384;

  f32x4 acc[4][2];
  #pragma unroll
  for (int mi = 0; mi < 4; ++mi)
    #pragma unroll
    for (int ni = 0; ni < 2; ++ni)
      acc[mi][ni] = (f32x4){0.f, 0.f, 0.f, 0.f};

  float4 sl0[4], sl1[4];          // A reg slots: A(x) -> slot (x&1)
  float4 Ev[4];                   // persistent E regs across a part-triplet

  const int rlo = lane & 15;
  const int khi = lane >> 4;
  const int wm = wave >> 2;       // 0..1: 64-row slab
  const int wn = wave & 3;        // 0..3: 32-col slab

  #define ISSUE_A(c) {                                                       \
    const int g_ = (c) / 3, part_ = (c) % 3;                                 \
    float4* dst_ = ((c) & 1) ? sl1 : sl0;                                    \
    _Pragma("unroll")                                                        \
    for (int i = 0; i < 4; ++i)                                              \
      dst_[i] = *(const float4*)((part_ == 0 ? eptr[i] : hptr[i])            \
                                 + g_ * 64 + cg * 4);                        \
  }

  #define WRITE_A(c, buf) {                                                  \
    const int part_ = (c) % 3;                                               \
    float4* src_ = ((c) & 1) ? sl1 : sl0;                                    \
    _Pragma("unroll")                                                        \
    for (int i = 0; i < 4; ++i){                                             \
      int row = rg * 4 + i;                                                  \
      float4 v;                                                              \
      if (part_ == 0){ Ev[i] = src_[i]; v = src_[i]; }                       \
      else if (part_ == 1) v = make_float4(Ev[i].x*src_[i].x,                \
          Ev[i].y*src_[i].y, Ev[i].z*src_[i].z, Ev[i].w*src_[i].w);          \
      else v = src_[i];                                                      \
      uint2 w; w.x = pack2(v.x, v.y); w.y = pack2(v.z, v.w);                 \
      int off = (row * 128 + cg * 8) ^ ((row & 7) << 4);                     \
      *(uint2*)(&sAl[buf][off]) = w;                                         \
    }                                                                        \
  }

  #define STAGE_B(c, buf) {                                                  \
    const char* srcb = wq + (size_t)(c) * 16384 + wave * 2048 + lane * 16;   \
    char* db = &sBl[buf][wave * 2048];                                       \
    GLL16(srcb,        db);                                                  \
    GLL16(srcb + 1024, db + 1024);                                           \
  }

  // ---- Prologue ----
  ISSUE_A(0);
  ISSUE_A(1);
  STAGE_B(0, 0);
  WRITE_A(0, 0);
  ISSUE_A(2);
  __syncthreads();

  // ---- Main loop (R6-proven structure) ----
  #pragma unroll
  for (int c = 0; c < NCHUNK; ++c){
    const int cur = c & 1;
    if (c + 1 < NCHUNK){
      STAGE_B(c + 1, cur ^ 1);
      WRITE_A(c + 1, cur ^ 1);
    }
    if (c + 3 < NCHUNK){
      ISSUE_A(c + 3);
    }
    #pragma unroll
    for (int ks = 0; ks < 2; ++ks){
      const int kb = (ks * 32 + khi * 8) * 2;
      s16x8 af[4], bfr[2];
      #pragma unroll
      for (int mi = 0; mi < 4; ++mi){
        int row = wm * 64 + mi * 16 + rlo;
        af[mi] = *(const s16x8*)(&sAl[cur][(row * 128 + kb) ^ ((row & 7) << 4)]);
      }
      #pragma unroll
      for (int ni = 0; ni < 2; ++ni){
        int col = wn * 32 + ni * 16 + rlo;
        bfr[ni] = *(const s16x8*)(&sBl[cur][(col * 128 + kb) ^ ((col & 7) << 4)]);
      }
      #pragma unroll
      for (int mi = 0; mi < 4; ++mi)
        #pragma unroll
        for (int ni = 0; ni < 2; ++ni)
          acc[mi][ni] = __builtin_amdgcn_mfma_f32_16x16x32_bf16(
              af[mi], bfr[ni], acc[mi][ni], 0, 0, 0);
    }
    if (c + 1 < NCHUNK) __syncthreads();
  }
  #undef ISSUE_A
  #undef WRITE_A
  #undef STAGE_B

  // ---- Epilogue: C -> LDS, segmented run-reduce over dst-sorted rows ----
  __syncthreads();                 // all MFMA LDS reads done; smem reusable
  float* Cs = (float*)smem;        // [128][128], bank-rotated by row
  #pragma unroll
  for (int mi = 0; mi < 4; ++mi)
    #pragma unroll
    for (int ni = 0; ni < 2; ++ni)
      #pragma unroll
      for (int r = 0; r < 4; ++r){
        int row = wm * 64 + mi * 16 + khi * 4 + r;
        int col = wn * 32 + ni * 16 + rlo;
        int cw = (col + ((row & 7) << 2)) & 127;
        Cs[row * 128 + cw] = acc[mi][ni][r];
      }
  __syncthreads();

  {
    const int col = tid & 127;
    const int q   = tid >> 7;          // 4 row-quarters
    int r0 = q << 5;
    if (q > 0 && sDst[r0] == sDst[r0 - 1]){
      int pd = sDst[r0 - 1];
      int rcap = (q << 5) + 32;
      while (r0 < rcap && sDst[r0] == pd) r0++;
    }
    const int rend = (q << 5) + 32;
    for (int r = r0; r < rend; ){
      int d = sDst[r];
      float s = 0.f;
      int rr = r;
      while (rr < 128 && sDst[rr] == d){
        s += Cs[rr * 128 + ((col + ((rr & 7) << 2)) & 127)];
        rr++;
      }
      if (d < n_nodes)
        atomicAdd(agg + (long)d * D + h * NB + col, s);
      r = rr;
    }
  }
}

__global__ __launch_bounds__(256) void finish(
    const float* __restrict__ agg, const int* __restrict__ cnt_i,
    const float* __restrict__ H, const float* __restrict__ bias_f,
    const float* __restrict__ bias_b, const float* __restrict__ gamma,
    const float* __restrict__ beta, float* __restrict__ out, int n_nodes)
{
  const int n = blockIdx.x;
  const int j = threadIdx.x;
  int cf = cnt_i[n], cb = cnt_i[n_nodes + n];
  float c = (float)(cf + cb); c = c < 1.f ? 1.f : c;
  float a = (agg[(long)n * D + j] + (float)cf * bias_f[j] + (float)cb * bias_b[j]) / c;
  float x = (a > 0.f ? a : LEAKY * a) + H[(long)n * D + j];
  float s1 = x, s2 = x * x;
  #pragma unroll
  for (int off = 32; off > 0; off >>= 1){
    s1 += __shfl_xor(s1, off);
    s2 += __shfl_xor(s2, off);
  }
  __shared__ float rs[8];
  if ((j & 63) == 0){ rs[j >> 6] = s1; rs[4 + (j >> 6)] = s2; }
  __syncthreads();
  float t1 = rs[0] + rs[1] + rs[2] + rs[3];
  float t2 = rs[4] + rs[5] + rs[6] + rs[7];
  float mu = t1 * (1.f / D);
  float var = t2 * (1.f / D) - mu * mu;
  float r = rsqrtf(var + EPS);
  out[(long)n * D + j] = (x - mu) * r * gamma[j] + beta[j];
}

extern "C" void kernel_launch(void* const* d_in, const int* in_sizes, int n_in,
                              void* d_out, int out_size, void* d_ws, size_t ws_size,
                              hipStream_t stream)
{
  const float* H      = (const float*)d_in[0];
  const float* E      = (const float*)d_in[1];
  const int*   ht     = (const int*)d_in[2];
  const float* W_fwd  = (const float*)d_in[3];
  const float* b_fwd  = (const float*)d_in[4];
  const float* W_back = (const float*)d_in[5];
  const float* b_back = (const float*)d_in[6];
  const float* gamma  = (const float*)d_in[7];
  const float* beta   = (const float*)d_in[8];
  float* out = (float*)d_out;

  const int n_nodes = in_sizes[0] / D;
  const int n_edges = in_sizes[2] / 2;
  const int N2 = 2 * n_nodes;
  const int NM = 2 * n_edges;

  char* p = (char*)d_ws;
  float* agg    = (float*)p;  p += (size_t)n_nodes * D * 4;
  int*   cnt_i  = (int*)p;    p += (size_t)N2 * 4;
  int*   cursor = (int*)p;    p += (size_t)N2 * 4;
  size_t zbytes = (size_t)(p - (char*)d_ws);          // agg + cnt + cursor
  int*   off    = (int*)p;    p += (size_t)N2 * 4;
  int*   bsum   = (int*)p;    p += 128 * 4;
  int*   bases  = (int*)p;    p += 128 * 4;
  int*   perm   = (int*)p;    p += (size_t)NM * 4;
  int*   dstS   = (int*)p;    p += (size_t)NM * 4;
  int*   hS     = (int*)p;    p += (size_t)NM * 4;
  unsigned short* Wimg = (unsigned short*)p;

  const int nscan = (N2 + 1023) / 1024;

  hipMemsetAsync(d_ws, 0, zbytes, stream);
  prep_w<<<(2 * 2 * NCHUNK * NB * BK) / 256, 256, 0, stream>>>(W_fwd, W_back, Wimg);
  count2<<<(n_edges + 255) / 256, 256, 0, stream>>>(ht, cnt_i, n_edges, n_nodes);
  scan_sums<<<nscan, 1024, 0, stream>>>(cnt_i, bsum, N2);
  scan_bases<<<1, 64, 0, stream>>>(bsum, bases, nscan);
  scan_off<<<nscan, 1024, 0, stream>>>(cnt_i, bases, off, N2);
  scatter_msgs<<<(NM + 255) / 256, 256, 0, stream>>>(ht, off, cursor, perm, dstS, hS,
                                                     n_edges, n_nodes);
  const int ntiles = (n_edges + TE - 1) / TE;
  edge_gemm<<<ntiles * 4, 512, 0, stream>>>(H, E, perm, dstS, hS, Wimg, agg,
                                            n_edges, n_nodes);
  finish<<<n_nodes, 256, 0, stream>>>(agg, cnt_i, H, b_fwd, b_back, gamma, beta,
                                      out, n_nodes);
}